// Round 1
// baseline (398.007 us; speedup 1.0000x reference)
//
#include <hip/hip_runtime.h>

// Multi-Scale Deformable Attention forward, fp32.
// Shapes (hardcoded to match reference setup):
//   value:  (B=2, Len=21760, nH=8, D=32) fp32
//   loc:    (B, Q=21760, nH, L=4, P=4, 2) fp32
//   attw:   (B, Q, nH, L, P) fp32
//   out:    (B, Q, nH*D=256) fp32
// Levels: (128,128),(64,64),(32,32),(16,16), starts 0,16384,20480,21504.

namespace {
constexpr int kB   = 2;
constexpr int kQ   = 21760;
constexpr int kHd  = 8;     // heads
constexpr int kD   = 32;    // channels per head
constexpr int kLen = 21760;
constexpr int kRow = kHd * kD;   // 256 floats per spatial position
}

__device__ __forceinline__ void fma4(float4& a, float w, const float4 v) {
    a.x = fmaf(w, v.x, a.x);
    a.y = fmaf(w, v.y, a.y);
    a.z = fmaf(w, v.z, a.z);
    a.w = fmaf(w, v.w, a.w);
}

__global__ __launch_bounds__(256) void msda_fwd(
    const float* __restrict__ value,
    const float* __restrict__ loc,
    const float* __restrict__ attw,
    float* __restrict__ out)
{
    const int t   = blockIdx.x * 256 + threadIdx.x;
    const int sub = t & 1;          // channel half: [sub*16, sub*16+16)
    const int g   = t >> 1;         // (b*Q + q)*8 + h
    const int h   = g & 7;
    const int bq  = g >> 3;         // b*Q + q
    const int b   = bq / kQ;

    const float* lp = loc  + (size_t)g * 32;   // L*P*2 = 32 floats per (b,q,h)
    const float* ap = attw + (size_t)g * 16;   // L*P   = 16 floats
    const float* vb = value + (size_t)b * kLen * kRow + h * kD + sub * 16;

    float4 acc0 = make_float4(0.f, 0.f, 0.f, 0.f);
    float4 acc1 = acc0, acc2 = acc0, acc3 = acc0;

    constexpr int Hs[4] = {128, 64, 32, 16};
    constexpr int Ws[4] = {128, 64, 32, 16};
    constexpr int Ss[4] = {0, 16384, 20480, 21504};

    #pragma unroll
    for (int l = 0; l < 4; ++l) {
        const int W = Ws[l];
        const int H = Hs[l];
        const int S = Ss[l];

        const float4 lc0 = *(const float4*)(lp + l * 8);
        const float4 lc1 = *(const float4*)(lp + l * 8 + 4);
        const float4 av  = *(const float4*)(ap + l * 4);

        const float lx[4] = {lc0.x, lc0.z, lc1.x, lc1.z};
        const float ly[4] = {lc0.y, lc0.w, lc1.y, lc1.w};
        const float aa[4] = {av.x,  av.y,  av.z,  av.w};

        #pragma unroll
        for (int p = 0; p < 4; ++p) {
            // grid_sample(align_corners=False): x = loc_x * W - 0.5
            const float x = fmaf(lx[p], (float)W, -0.5f);
            const float y = fmaf(ly[p], (float)H, -0.5f);
            const float x0f = floorf(x);
            const float y0f = floorf(y);
            const float fx = x - x0f;
            const float fy = y - y0f;
            const int   x0 = (int)x0f;
            const int   y0 = (int)y0f;
            const float a  = aa[p];
            // attention weight folded into tap weights
            const float w00 = a * (1.f - fx) * (1.f - fy);
            const float w01 = a * fx * (1.f - fy);
            const float w10 = a * (1.f - fx) * fy;
            const float w11 = a * fx * fy;

            #pragma unroll
            for (int dy = 0; dy < 2; ++dy) {
                const int  yy = y0 + dy;
                const bool vy = (unsigned)yy < (unsigned)H;
                const int  yc = min(max(yy, 0), H - 1);
                #pragma unroll
                for (int dx = 0; dx < 2; ++dx) {
                    const int  xx = x0 + dx;
                    const bool ok = vy && ((unsigned)xx < (unsigned)W);
                    const int  xc = min(max(xx, 0), W - 1);
                    float w = dy ? (dx ? w11 : w10) : (dx ? w01 : w00);
                    w = ok ? w : 0.f;
                    const float4* r =
                        (const float4*)(vb + (size_t)(S + yc * W + xc) * kRow);
                    const float4 v0 = r[0];
                    const float4 v1 = r[1];
                    const float4 v2 = r[2];
                    const float4 v3 = r[3];
                    fma4(acc0, w, v0);
                    fma4(acc1, w, v1);
                    fma4(acc2, w, v2);
                    fma4(acc3, w, v3);
                }
            }
        }
    }

    float* op = out + (size_t)bq * kRow + h * kD + sub * 16;
    ((float4*)op)[0] = acc0;
    ((float4*)op)[1] = acc1;
    ((float4*)op)[2] = acc2;
    ((float4*)op)[3] = acc3;
}

extern "C" void kernel_launch(void* const* d_in, const int* in_sizes, int n_in,
                              void* d_out, int out_size, void* d_ws, size_t ws_size,
                              hipStream_t stream) {
    const float* value = (const float*)d_in[0];
    // d_in[1] = value_spatial_shapes (unused, compile-time constants)
    // d_in[2] = value_level_start_index (unused)
    const float* loc   = (const float*)d_in[3];
    const float* attw  = (const float*)d_in[4];
    // d_in[5] = im2col_step (unused)
    float* out = (float*)d_out;

    const int total_threads = kB * kQ * kHd * 2;   // 696320
    const int block = 256;
    const int grid  = total_threads / block;       // 2720 exactly

    msda_fwd<<<grid, block, 0, stream>>>(value, loc, attw, out);
}

// Round 2
// 218.384 us; speedup vs baseline: 1.8225x; 1.8225x over previous
//
#include <hip/hip_runtime.h>

// Multi-Scale Deformable Attention forward, fp32.
//   value:  (B=2, Len=21760, nH=8, D=32) fp32
//   loc:    (B, Q=21760, nH, L=4, P=4, 2) fp32
//   attw:   (B, Q, nH, L, P) fp32
//   out:    (B, Q, nH*D=256) fp32
// Levels: (128,128),(64,64),(32,32),(16,16), starts 0,16384,20480,21504.
//
// 8 threads per (b,q,h): thread `sub` owns channels [sub*4, sub*4+4).
// Each bilinear corner -> one float4 load per thread; 8 lanes cover the
// full 128-B row segment of that head. Maximizes independent loads in
// flight (latency-bound gather per round-1 counters).

namespace {
constexpr int kB   = 2;
constexpr int kQ   = 21760;
constexpr int kHd  = 8;
constexpr int kD   = 32;
constexpr int kLen = 21760;
constexpr int kRow = kHd * kD;   // 256 floats per spatial position
}

__device__ __forceinline__ void fma4(float4& a, float w, const float4 v) {
    a.x = fmaf(w, v.x, a.x);
    a.y = fmaf(w, v.y, a.y);
    a.z = fmaf(w, v.z, a.z);
    a.w = fmaf(w, v.w, a.w);
}

__global__ __launch_bounds__(256, 4) void msda_fwd(
    const float* __restrict__ value,
    const float* __restrict__ loc,
    const float* __restrict__ attw,
    float* __restrict__ out)
{
    const int t   = blockIdx.x * 256 + threadIdx.x;
    const int sub = t & 7;          // float4 slot within the 32-ch head
    const int g   = t >> 3;         // (b*Q + q)*8 + h
    const int h   = g & 7;
    const int bq  = g >> 3;         // b*Q + q
    const int b   = (bq >= kQ) ? 1 : 0;   // B == 2, avoid idiv

    const float4* lp4 = (const float4*)(loc  + (size_t)g * 32);
    const float4* ap4 = (const float4*)(attw + (size_t)g * 16);
    const float*  vb  = value + (size_t)b * kLen * kRow + h * kD + sub * 4;

    float4 acc = make_float4(0.f, 0.f, 0.f, 0.f);

    constexpr int Hs[4] = {128, 64, 32, 16};
    constexpr int Ws[4] = {128, 64, 32, 16};
    constexpr int Ss[4] = {0, 16384, 20480, 21504};

    #pragma unroll
    for (int l = 0; l < 4; ++l) {
        const int W = Ws[l];
        const int H = Hs[l];
        const int S = Ss[l];

        const float4 lc0 = lp4[2 * l];
        const float4 lc1 = lp4[2 * l + 1];
        const float4 av  = ap4[l];

        const float lx[4] = {lc0.x, lc0.z, lc1.x, lc1.z};
        const float ly[4] = {lc0.y, lc0.w, lc1.y, lc1.w};
        const float aa[4] = {av.x,  av.y,  av.z,  av.w};

        #pragma unroll
        for (int p = 0; p < 4; ++p) {
            // grid_sample(align_corners=False): x = loc_x * W - 0.5
            const float x = fmaf(lx[p], (float)W, -0.5f);
            const float y = fmaf(ly[p], (float)H, -0.5f);
            const float x0f = floorf(x);
            const float y0f = floorf(y);
            const float fx = x - x0f;
            const float fy = y - y0f;
            const int   x0 = (int)x0f;
            const int   y0 = (int)y0f;
            const float a  = aa[p];

            const bool vx0 = (unsigned)x0       < (unsigned)W;
            const bool vx1 = (unsigned)(x0 + 1) < (unsigned)W;
            const bool vy0 = (unsigned)y0       < (unsigned)H;
            const bool vy1 = (unsigned)(y0 + 1) < (unsigned)H;

            const int xc0 = min(max(x0, 0),     W - 1);
            const int xc1 = min(max(x0 + 1, 0), W - 1);
            const int yc0 = min(max(y0, 0),     H - 1);
            const int yc1 = min(max(y0 + 1, 0), H - 1);

            float w00 = a * (1.f - fx) * (1.f - fy);
            float w01 = a * fx * (1.f - fy);
            float w10 = a * (1.f - fx) * fy;
            float w11 = a * fx * fy;
            w00 = (vy0 && vx0) ? w00 : 0.f;
            w01 = (vy0 && vx1) ? w01 : 0.f;
            w10 = (vy1 && vx0) ? w10 : 0.f;
            w11 = (vy1 && vx1) ? w11 : 0.f;

            const int r0 = (S + yc0 * W) * kRow;
            const int r1 = (S + yc1 * W) * kRow;
            const float4 v00 = *(const float4*)(vb + r0 + xc0 * kRow);
            const float4 v01 = *(const float4*)(vb + r0 + xc1 * kRow);
            const float4 v10 = *(const float4*)(vb + r1 + xc0 * kRow);
            const float4 v11 = *(const float4*)(vb + r1 + xc1 * kRow);

            fma4(acc, w00, v00);
            fma4(acc, w01, v01);
            fma4(acc, w10, v10);
            fma4(acc, w11, v11);
        }
    }

    *(float4*)(out + (size_t)bq * kRow + h * kD + sub * 4) = acc;
}

extern "C" void kernel_launch(void* const* d_in, const int* in_sizes, int n_in,
                              void* d_out, int out_size, void* d_ws, size_t ws_size,
                              hipStream_t stream) {
    const float* value = (const float*)d_in[0];
    const float* loc   = (const float*)d_in[3];
    const float* attw  = (const float*)d_in[4];
    float* out = (float*)d_out;

    const int total_threads = kB * kQ * kHd * 8;   // 2,785,280
    const int block = 256;
    const int grid  = total_threads / block;       // 10880 exactly

    msda_fwd<<<grid, block, 0, stream>>>(value, loc, attw, out);
}

// Round 3
// 213.350 us; speedup vs baseline: 1.8655x; 1.0236x over previous
//
#include <hip/hip_runtime.h>

// Multi-Scale Deformable Attention forward, fp32.
//   value:  (B=2, Len=21760, nH=8, D=32) fp32
//   loc:    (B, Q=21760, nH, L=4, P=4, 2) fp32
//   attw:   (B, Q, nH, L, P) fp32
//   out:    (B, Q, nH*D=256) fp32
// Levels: (128,128),(64,64),(32,32),(16,16), starts 0,16384,20480,21504.
//
// 8 threads per (b,q,h); thread `sub` owns channels [sub*4, sub*4+4).
// Per level: compute ALL 16 tap byte-offsets + folded weights, then issue
// 16 independent float4 gathers, then accumulate — forces deep MLP
// (round-2 showed latency-bound: VALU 28%, BW 44%, VGPR 36).

namespace {
constexpr int kB   = 2;
constexpr int kQ   = 21760;
constexpr int kHd  = 8;
constexpr int kD   = 32;
constexpr int kLen = 21760;
constexpr int kRow = kHd * kD;   // 256 floats per spatial position
}

__device__ __forceinline__ void fma4(float4& a, float w, const float4 v) {
    a.x = fmaf(w, v.x, a.x);
    a.y = fmaf(w, v.y, a.y);
    a.z = fmaf(w, v.z, a.z);
    a.w = fmaf(w, v.w, a.w);
}

__global__ __launch_bounds__(256, 4) void msda_fwd(
    const float* __restrict__ value,
    const float* __restrict__ loc,
    const float* __restrict__ attw,
    float* __restrict__ out)
{
    const int t   = blockIdx.x * 256 + threadIdx.x;
    const int sub = t & 7;          // float4 slot within the 32-ch head
    const int g   = t >> 3;         // (b*Q + q)*8 + h
    const int h   = g & 7;
    const int bq  = g >> 3;         // b*Q + q
    const int b   = (bq >= kQ) ? 1 : 0;   // B == 2, avoid idiv

    const float4* lp4 = (const float4*)(loc  + (size_t)g * 32);
    const float4* ap4 = (const float4*)(attw + (size_t)g * 16);
    // 32-bit byte offset of this thread's channel slice within `value`
    const int thrbase = ((b * kLen * kRow) + h * kD + sub * 4) * 4;

    float4 acc = make_float4(0.f, 0.f, 0.f, 0.f);

    constexpr int Hs[4] = {128, 64, 32, 16};
    constexpr int Ws[4] = {128, 64, 32, 16};
    constexpr int Ss[4] = {0, 16384, 20480, 21504};

    #pragma unroll
    for (int l = 0; l < 4; ++l) {
        const int W = Ws[l];
        const int H = Hs[l];
        const int base = thrbase + (Ss[l] << 10);   // S * kRow * 4 bytes

        const float4 lc0 = lp4[2 * l];
        const float4 lc1 = lp4[2 * l + 1];
        const float4 av  = ap4[l];

        const float lx[4] = {lc0.x, lc0.z, lc1.x, lc1.z};
        const float ly[4] = {lc0.y, lc0.w, lc1.y, lc1.w};
        const float aa[4] = {av.x,  av.y,  av.z,  av.w};

        int   offs[16];
        float ws[16];

        #pragma unroll
        for (int p = 0; p < 4; ++p) {
            // grid_sample(align_corners=False): x = loc_x * W - 0.5
            const float x = fmaf(lx[p], (float)W, -0.5f);
            const float y = fmaf(ly[p], (float)H, -0.5f);
            const float x0f = floorf(x);
            const float y0f = floorf(y);
            const float fx = x - x0f;
            const float fy = y - y0f;
            const int   x0 = (int)x0f;
            const int   y0 = (int)y0f;
            const float a  = aa[p];

            const bool vx0 = (unsigned)x0       < (unsigned)W;
            const bool vx1 = (unsigned)(x0 + 1) < (unsigned)W;
            const bool vy0 = (unsigned)y0       < (unsigned)H;
            const bool vy1 = (unsigned)(y0 + 1) < (unsigned)H;

            const int xc0 = min(max(x0, 0),     W - 1);
            const int xc1 = min(max(x0 + 1, 0), W - 1);
            const int yc0 = min(max(y0, 0),     H - 1);
            const int yc1 = min(max(y0 + 1, 0), H - 1);

            float w00 = a * (1.f - fx) * (1.f - fy);
            float w01 = a * fx * (1.f - fy);
            float w10 = a * (1.f - fx) * fy;
            float w11 = a * fx * fy;

            ws[p * 4 + 0] = (vy0 && vx0) ? w00 : 0.f;
            ws[p * 4 + 1] = (vy0 && vx1) ? w01 : 0.f;
            ws[p * 4 + 2] = (vy1 && vx0) ? w10 : 0.f;
            ws[p * 4 + 3] = (vy1 && vx1) ? w11 : 0.f;

            const int r0 = yc0 * W;   // W is power of two -> shift
            const int r1 = yc1 * W;
            offs[p * 4 + 0] = base + ((r0 + xc0) << 10);
            offs[p * 4 + 1] = base + ((r0 + xc1) << 10);
            offs[p * 4 + 2] = base + ((r1 + xc0) << 10);
            offs[p * 4 + 3] = base + ((r1 + xc1) << 10);
        }

        float4 tv[16];
        #pragma unroll
        for (int i = 0; i < 16; ++i)
            tv[i] = *(const float4*)((const char*)value + offs[i]);

        #pragma unroll
        for (int i = 0; i < 16; ++i)
            fma4(acc, ws[i], tv[i]);
    }

    *(float4*)(out + (size_t)bq * kRow + h * kD + sub * 4) = acc;
}

extern "C" void kernel_launch(void* const* d_in, const int* in_sizes, int n_in,
                              void* d_out, int out_size, void* d_ws, size_t ws_size,
                              hipStream_t stream) {
    const float* value = (const float*)d_in[0];
    const float* loc   = (const float*)d_in[3];
    const float* attw  = (const float*)d_in[4];
    float* out = (float*)d_out;

    const int total_threads = kB * kQ * kHd * 8;   // 2,785,280
    const int block = 256;
    const int grid  = total_threads / block;       // 10880 exactly

    msda_fwd<<<grid, block, 0, stream>>>(value, loc, attw, out);
}